// Round 1
// baseline (2015.974 us; speedup 1.0000x reference)
//
#include <hip/hip_runtime.h>
#include <hip/hip_bf16.h>
#include <math.h>

// Problem constants
#define D_MODEL 1024
#define D_STATE 16
#define D_CONV 4
#define D_INNER 2048
#define DT_RANK 64
#define BATCH 2
#define SEQ_LEN 1024
#define T_TOTAL (BATCH * SEQ_LEN)   // 2048 rows

// ---------------------------------------------------------------------------
// Generic tiled fp32 GEMM: C[m][n] = sum_k A[m*lda + k] * Bw[n*ldb + k]
// (A row-major MxK, B stored as NxK row-major -> "B transposed" dot over K)
// ---------------------------------------------------------------------------
#define BM 64
#define BN 64
#define BK 16

__global__ __launch_bounds__(256) void gemm_bt(
    const float* __restrict__ A, int lda,
    const float* __restrict__ Bw, int ldb,
    float* __restrict__ C, int ldc,
    int M, int N, int K)
{
    __shared__ float As[BK][BM + 1];
    __shared__ float Bs[BK][BN + 1];

    const int tid = threadIdx.x;
    const int row0 = blockIdx.y * BM;
    const int col0 = blockIdx.x * BN;
    const int ty = tid >> 4;    // 0..15
    const int tx = tid & 15;    // 0..15

    float acc[4][4] = {};

    for (int k0 = 0; k0 < K; k0 += BK) {
        // Load A tile: BM x BK (64x16 = 1024 elems, 4 per thread)
#pragma unroll
        for (int i = 0; i < 4; ++i) {
            int idx = tid + i * 256;
            int m = idx >> 4;
            int k = idx & 15;
            int gm = row0 + m;
            float v = 0.f;
            if (gm < M) v = A[(size_t)gm * lda + (k0 + k)];
            As[k][m] = v;
        }
        // Load B tile: BN x BK
#pragma unroll
        for (int i = 0; i < 4; ++i) {
            int idx = tid + i * 256;
            int n = idx >> 4;
            int k = idx & 15;
            int gn = col0 + n;
            float v = 0.f;
            if (gn < N) v = Bw[(size_t)gn * ldb + (k0 + k)];
            Bs[k][n] = v;
        }
        __syncthreads();

#pragma unroll
        for (int k = 0; k < BK; ++k) {
            float a[4], b[4];
#pragma unroll
            for (int i = 0; i < 4; ++i) a[i] = As[k][ty * 4 + i];
#pragma unroll
            for (int j = 0; j < 4; ++j) b[j] = Bs[k][tx * 4 + j];
#pragma unroll
            for (int i = 0; i < 4; ++i)
#pragma unroll
                for (int j = 0; j < 4; ++j)
                    acc[i][j] += a[i] * b[j];
        }
        __syncthreads();
    }

#pragma unroll
    for (int i = 0; i < 4; ++i) {
        int gm = row0 + ty * 4 + i;
        if (gm >= M) continue;
#pragma unroll
        for (int j = 0; j < 4; ++j) {
            int gn = col0 + tx * 4 + j;
            if (gn < N) C[(size_t)gm * ldc + gn] = acc[i][j];
        }
    }
}

// ---------------------------------------------------------------------------
// Causal depthwise conv (K=4) + bias + SiLU.
// xz: (B, L, 2*D_INNER) -> take first D_INNER channels. out xc: (B, L, D_INNER)
// ---------------------------------------------------------------------------
__global__ __launch_bounds__(256) void conv_silu_kernel(
    const float* __restrict__ xz,
    const float* __restrict__ cw,   // (D_INNER, 1, 4)
    const float* __restrict__ cb,   // (D_INNER,)
    float* __restrict__ xc)
{
    int idx = blockIdx.x * 256 + threadIdx.x;   // over B*L*D_INNER
    int d = idx & (D_INNER - 1);
    int t = (idx >> 11) & (SEQ_LEN - 1);
    int b = idx >> 21;

    const float* base = xz + ((size_t)b * SEQ_LEN + t) * (2 * D_INNER) + d;
    float w0 = cw[d * 4 + 0], w1 = cw[d * 4 + 1], w2 = cw[d * 4 + 2], w3 = cw[d * 4 + 3];
    float acc = cb[d];
    if (t >= 3) acc += w0 * base[-3 * (2 * D_INNER)];
    if (t >= 2) acc += w1 * base[-2 * (2 * D_INNER)];
    if (t >= 1) acc += w2 * base[-1 * (2 * D_INNER)];
    acc += w3 * base[0];
    // SiLU
    float s = acc / (1.f + __expf(-acc));
    xc[idx] = s;
}

// ---------------------------------------------------------------------------
// dt = softplus(dt_raw + b_dt[d]) over (B, L, D_INNER)
// ---------------------------------------------------------------------------
__global__ __launch_bounds__(256) void dt_softplus_kernel(
    float* __restrict__ dtb, const float* __restrict__ b_dt)
{
    int idx = blockIdx.x * 256 + threadIdx.x;
    int d = idx & (D_INNER - 1);
    float x = dtb[idx] + b_dt[d];
    float sp = (x > 20.f) ? x : log1pf(__expf(x));
    dtb[idx] = sp;
}

// ---------------------------------------------------------------------------
// Selective scan. One thread per (b, d, n): 2*2048*16 = 65536 threads.
// Within a block of 256: n = tid&15, d_local = tid>>4 (16 d's per block).
// Reduce y over n with 16-lane shfl_xor, fuse (y + x*D)*silu(z) epilogue.
// ---------------------------------------------------------------------------
__global__ __launch_bounds__(256) void scan_kernel(
    const float* __restrict__ dbc,    // (B, L, 96)
    const float* __restrict__ dtv,    // (B, L, D_INNER)
    const float* __restrict__ xc,     // (B, L, D_INNER)
    const float* __restrict__ xz,     // (B, L, 2*D_INNER) for z
    const float* __restrict__ A_log,  // (D_INNER, 16)
    const float* __restrict__ D_skip, // (D_INNER,)
    float* __restrict__ y)            // (B, L, D_INNER)
{
    const int tid = threadIdx.x;
    const int n = tid & 15;
    const int dl = tid >> 4;                 // 0..15
    const int b = blockIdx.x & 1;
    const int d = (blockIdx.x >> 1) * 16 + dl;

    const float A = -__expf(A_log[d * 16 + n]);
    const float Dv = D_skip[d];

    const float* dbcb = dbc + (size_t)b * SEQ_LEN * 96;
    const float* dtb  = dtv + (size_t)b * SEQ_LEN * D_INNER + d;
    const float* xcb  = xc  + (size_t)b * SEQ_LEN * D_INNER + d;
    const float* zb   = xz  + (size_t)b * SEQ_LEN * (2 * D_INNER) + D_INNER + d;
    float* yb = y + (size_t)b * SEQ_LEN * D_INNER + d;

    float h = 0.f;
    for (int t = 0; t < SEQ_LEN; ++t) {
        float dtval = dtb[(size_t)t * D_INNER];
        float xv = xcb[(size_t)t * D_INNER];
        float Bv = dbcb[t * 96 + DT_RANK + n];
        float Cv = dbcb[t * 96 + DT_RANK + D_STATE + n];
        float a = __expf(dtval * A);
        h = a * h + (xv * dtval) * Bv;
        float p = Cv * h;
        // reduce over the 16 n-lanes
        p += __shfl_xor(p, 1);
        p += __shfl_xor(p, 2);
        p += __shfl_xor(p, 4);
        p += __shfl_xor(p, 8);
        if (n == 0) {
            float zv = zb[(size_t)t * (2 * D_INNER)];
            float sig = 1.f / (1.f + __expf(-zv));
            yb[(size_t)t * D_INNER] = (p + xv * Dv) * (zv * sig);
        }
    }
}

// ---------------------------------------------------------------------------
// Launch
// ---------------------------------------------------------------------------
extern "C" void kernel_launch(void* const* d_in, const int* in_sizes, int n_in,
                              void* d_out, int out_size, void* d_ws, size_t ws_size,
                              hipStream_t stream)
{
    const float* x      = (const float*)d_in[0];  // (2,1024,1024)
    const float* W_in   = (const float*)d_in[1];  // (4096,1024)
    const float* conv_w = (const float*)d_in[2];  // (2048,1,4)
    const float* conv_b = (const float*)d_in[3];  // (2048,)
    const float* W_x    = (const float*)d_in[4];  // (96,2048)
    const float* W_dt   = (const float*)d_in[5];  // (2048,64)
    const float* b_dt   = (const float*)d_in[6];  // (2048,)
    const float* A_log  = (const float*)d_in[7];  // (2048,16)
    const float* D_skip = (const float*)d_in[8];  // (2048,)
    const float* W_out  = (const float*)d_in[9];  // (1024,2048)
    float* out = (float*)d_out;                   // (2,1024,1024)

    float* ws = (float*)d_ws;
    float* xz    = ws;                                        // 2*1024*4096
    float* xc    = xz + (size_t)T_TOTAL * 2 * D_INNER;        // 2*1024*2048
    float* dbc   = xc + (size_t)T_TOTAL * D_INNER;            // 2*1024*96
    float* dtbuf = dbc + (size_t)T_TOTAL * 96;                // 2*1024*2048
    float* ybuf  = dtbuf + (size_t)T_TOTAL * D_INNER;         // 2*1024*2048

    // 1. xz = x @ W_in^T : M=2048, N=4096, K=1024
    {
        dim3 grid((2 * D_INNER) / BN, T_TOTAL / BM);
        gemm_bt<<<grid, 256, 0, stream>>>(x, D_MODEL, W_in, D_MODEL,
                                          xz, 2 * D_INNER,
                                          T_TOTAL, 2 * D_INNER, D_MODEL);
    }
    // 2. conv + silu
    {
        int total = T_TOTAL * D_INNER;
        conv_silu_kernel<<<total / 256, 256, 0, stream>>>(xz, conv_w, conv_b, xc);
    }
    // 3. dbc = xc @ W_x^T : M=2048, N=96, K=2048
    {
        dim3 grid((96 + BN - 1) / BN, T_TOTAL / BM);
        gemm_bt<<<grid, 256, 0, stream>>>(xc, D_INNER, W_x, D_INNER,
                                          dbc, 96,
                                          T_TOTAL, 96, D_INNER);
    }
    // 4. dt_raw = dbc[:, :64] @ W_dt^T : M=2048, N=2048, K=64
    {
        dim3 grid(D_INNER / BN, T_TOTAL / BM);
        gemm_bt<<<grid, 256, 0, stream>>>(dbc, 96, W_dt, DT_RANK,
                                          dtbuf, D_INNER,
                                          T_TOTAL, D_INNER, DT_RANK);
    }
    // 5. dt = softplus(dt_raw + b_dt)
    {
        int total = T_TOTAL * D_INNER;
        dt_softplus_kernel<<<total / 256, 256, 0, stream>>>(dtbuf, b_dt);
    }
    // 6. selective scan + epilogue
    {
        int nblocks = BATCH * (D_INNER / 16);   // 256
        scan_kernel<<<nblocks, 256, 0, stream>>>(dbc, dtbuf, xc, xz,
                                                 A_log, D_skip, ybuf);
    }
    // 7. out = y @ W_out^T : M=2048, N=1024, K=2048
    {
        dim3 grid(D_MODEL / BN, T_TOTAL / BM);
        gemm_bt<<<grid, 256, 0, stream>>>(ybuf, D_INNER, W_out, D_INNER,
                                          out, D_MODEL,
                                          T_TOTAL, D_MODEL, D_INNER);
    }
}

// Round 6
// 599.491 us; speedup vs baseline: 3.3628x; 3.3628x over previous
//
#include <hip/hip_runtime.h>
#include <hip/hip_bf16.h>
#include <math.h>

// Problem constants
#define D_MODEL 1024
#define D_STATE 16
#define D_INNER 2048
#define DT_RANK 64
#define BATCH 2
#define SEQ_LEN 1024
#define T_TOTAL (BATCH * SEQ_LEN)   // 2048 rows

// Scan chunking
#define NC 16
#define CL 64

typedef unsigned short u16;
typedef __bf16 bf16x8 __attribute__((ext_vector_type(8)));
typedef float f32x4 __attribute__((ext_vector_type(4)));

__device__ __forceinline__ u16 f2bf(float f) {
    unsigned u = __builtin_bit_cast(unsigned, f);
    u += 0x7FFFu + ((u >> 16) & 1u);   // RNE
    return (u16)(u >> 16);
}

#define GLOAD_LDS16(g, l) \
    __builtin_amdgcn_global_load_lds((const __attribute__((address_space(1))) void*)(g), \
                                     (__attribute__((address_space(3))) void*)(l), 16, 0, 0)

// ---------------------------------------------------------------------------
// fp32 -> bf16 cast, 4 floats/thread, packed 8B store. nelem % 1024 == 0.
// ---------------------------------------------------------------------------
__global__ __launch_bounds__(256) void cast_bf16_kernel(
    const float* __restrict__ in, u16* __restrict__ out)
{
    int i = blockIdx.x * 256 + threadIdx.x;
    float4 v = ((const float4*)in)[i];
    unsigned lo = (unsigned)f2bf(v.x) | ((unsigned)f2bf(v.y) << 16);
    unsigned hi = (unsigned)f2bf(v.z) | ((unsigned)f2bf(v.w) << 16);
    ((uint2*)out)[i] = make_uint2(lo, hi);
}

// ---------------------------------------------------------------------------
// bf16 MFMA GEMM (m97 structure): C[m][n] = sum_k A[m][k] * Bw[n][k], fp32 out.
// 128x128 tile, BK=32, 4 waves (2x2), 4x4 16x16x32 frags per wave.
// M, N, K must be multiples of 128/128/32. A: MxK bf16, Bw: NxK bf16.
// ---------------------------------------------------------------------------
__global__ __launch_bounds__(256) void gemm_bf16_bt(
    const u16* __restrict__ A, int lda,
    const u16* __restrict__ Bw, int ldb,
    float* __restrict__ C, int ldc, int K)
{
    __shared__ u16 As[128][32];
    __shared__ u16 Bs[128][32];

    const int tid  = threadIdx.x;
    const int lane = tid & 63;
    const int wave = tid >> 6;
    const int wr   = wave >> 1;
    const int wc   = wave & 1;
    const int row0 = blockIdx.y * 128;
    const int col0 = blockIdx.x * 128;

    // staging coords: each thread loads 8 contiguous bf16 (16B)
    const int srow = tid >> 2;          // 0..63
    const int scol = (tid & 3) * 8;

    const u16* ag = A  + (size_t)(row0 + srow) * lda + scol;
    const u16* bg = Bw + (size_t)(col0 + srow) * ldb + scol;
    // LDS dest: wave-uniform base; HW adds lane*16B
    u16* asl = &As[0][0] + wave * 512;
    u16* bsl = &Bs[0][0] + wave * 512;

    f32x4 acc[4][4];
#pragma unroll
    for (int m = 0; m < 4; ++m)
#pragma unroll
        for (int n = 0; n < 4; ++n)
            acc[m][n] = (f32x4){0.f, 0.f, 0.f, 0.f};

    const int fr = lane & 15;           // frag row (A) / col (B)
    const int kh = (lane >> 4) * 8;     // k-offset of this lane's 8 elems

    for (int k0 = 0; k0 < K; k0 += 32) {
        GLOAD_LDS16(ag + k0,                      asl);
        GLOAD_LDS16(ag + k0 + (size_t)64 * lda,   asl + 2048);
        GLOAD_LDS16(bg + k0,                      bsl);
        GLOAD_LDS16(bg + k0 + (size_t)64 * ldb,   bsl + 2048);
        __syncthreads();   // drains vmcnt (global_load_lds) + barrier

        bf16x8 af[4], bf[4];
#pragma unroll
        for (int m = 0; m < 4; ++m)
            af[m] = *(const bf16x8*)&As[wr * 64 + m * 16 + fr][kh];
#pragma unroll
        for (int n = 0; n < 4; ++n)
            bf[n] = *(const bf16x8*)&Bs[wc * 64 + n * 16 + fr][kh];
#pragma unroll
        for (int m = 0; m < 4; ++m)
#pragma unroll
            for (int n = 0; n < 4; ++n)
                acc[m][n] = __builtin_amdgcn_mfma_f32_16x16x32_bf16(
                    af[m], bf[n], acc[m][n], 0, 0, 0);
        __syncthreads();
    }

    // C/D layout (m89-verified): col = lane&15, row = (lane>>4)*4 + reg
    const int crow = (lane >> 4) * 4;
#pragma unroll
    for (int m = 0; m < 4; ++m) {
        const int gr = row0 + wr * 64 + m * 16 + crow;
#pragma unroll
        for (int n = 0; n < 4; ++n) {
            const int gc = col0 + wc * 64 + n * 16 + fr;
#pragma unroll
            for (int r = 0; r < 4; ++r)
                C[(size_t)(gr + r) * ldc + gc] = acc[m][n][r];
        }
    }
}

// ---------------------------------------------------------------------------
// Small fp32 tiled GEMM (kept for the two tiny GEMMs)
// ---------------------------------------------------------------------------
#define BM 64
#define BN 64
#define BK 16

__global__ __launch_bounds__(256) void gemm_bt(
    const float* __restrict__ A, int lda,
    const float* __restrict__ Bw, int ldb,
    float* __restrict__ C, int ldc,
    int M, int N, int K)
{
    __shared__ float As[BK][BM + 1];
    __shared__ float Bs[BK][BN + 1];

    const int tid = threadIdx.x;
    const int row0 = blockIdx.y * BM;
    const int col0 = blockIdx.x * BN;
    const int ty = tid >> 4;
    const int tx = tid & 15;

    float acc[4][4] = {};

    for (int k0 = 0; k0 < K; k0 += BK) {
#pragma unroll
        for (int i = 0; i < 4; ++i) {
            int idx = tid + i * 256;
            int m = idx >> 4;
            int k = idx & 15;
            int gm = row0 + m;
            float v = 0.f;
            if (gm < M) v = A[(size_t)gm * lda + (k0 + k)];
            As[k][m] = v;
        }
#pragma unroll
        for (int i = 0; i < 4; ++i) {
            int idx = tid + i * 256;
            int n = idx >> 4;
            int k = idx & 15;
            int gn = col0 + n;
            float v = 0.f;
            if (gn < N) v = Bw[(size_t)gn * ldb + (k0 + k)];
            Bs[k][n] = v;
        }
        __syncthreads();

#pragma unroll
        for (int k = 0; k < BK; ++k) {
            float a[4], b[4];
#pragma unroll
            for (int i = 0; i < 4; ++i) a[i] = As[k][ty * 4 + i];
#pragma unroll
            for (int j = 0; j < 4; ++j) b[j] = Bs[k][tx * 4 + j];
#pragma unroll
            for (int i = 0; i < 4; ++i)
#pragma unroll
                for (int j = 0; j < 4; ++j)
                    acc[i][j] += a[i] * b[j];
        }
        __syncthreads();
    }

#pragma unroll
    for (int i = 0; i < 4; ++i) {
        int gm = row0 + ty * 4 + i;
        if (gm >= M) continue;
#pragma unroll
        for (int j = 0; j < 4; ++j) {
            int gn = col0 + tx * 4 + j;
            if (gn < N) C[(size_t)gm * ldc + gn] = acc[i][j];
        }
    }
}

// ---------------------------------------------------------------------------
// Causal depthwise conv (K=4) + bias + SiLU.
// ---------------------------------------------------------------------------
__global__ __launch_bounds__(256) void conv_silu_kernel(
    const float* __restrict__ xz,
    const float* __restrict__ cw,
    const float* __restrict__ cb,
    float* __restrict__ xc)
{
    int idx = blockIdx.x * 256 + threadIdx.x;
    int d = idx & (D_INNER - 1);
    int t = (idx >> 11) & (SEQ_LEN - 1);
    int b = idx >> 21;

    const float* base = xz + ((size_t)b * SEQ_LEN + t) * (2 * D_INNER) + d;
    float w0 = cw[d * 4 + 0], w1 = cw[d * 4 + 1], w2 = cw[d * 4 + 2], w3 = cw[d * 4 + 3];
    float acc = cb[d];
    if (t >= 3) acc += w0 * base[-3 * (2 * D_INNER)];
    if (t >= 2) acc += w1 * base[-2 * (2 * D_INNER)];
    if (t >= 1) acc += w2 * base[-1 * (2 * D_INNER)];
    acc += w3 * base[0];
    float s = acc / (1.f + __expf(-acc));
    xc[idx] = s;
}

// ---------------------------------------------------------------------------
// dt = softplus(dt_raw + b_dt[d])
// ---------------------------------------------------------------------------
__global__ __launch_bounds__(256) void dt_softplus_kernel(
    float* __restrict__ dtb, const float* __restrict__ b_dt)
{
    int idx = blockIdx.x * 256 + threadIdx.x;
    int d = idx & (D_INNER - 1);
    float x = dtb[idx] + b_dt[d];
    float sp = (x > 20.f) ? x : log1pf(__expf(x));
    dtb[idx] = sp;
}

// ---------------------------------------------------------------------------
// Chunked selective scan (A: local scan -> hf,P; B: inter-chunk -> H0;
// C: re-run from H0 with fused epilogue, emitting y as bf16 for the out-GEMM).
// ---------------------------------------------------------------------------
__global__ __launch_bounds__(256) void scan_phaseA(
    const float* __restrict__ dbc,
    const float* __restrict__ dtv,
    const float* __restrict__ xc,
    const float* __restrict__ A_log,
    float* __restrict__ hf,
    float* __restrict__ Pf)
{
    __shared__ float sB[CL][16];
    __shared__ float sdt[CL][16];
    __shared__ float sx[CL][16];

    const int tid = threadIdx.x;
    const int n  = tid & 15;
    const int dl = tid >> 4;
    const int c  = blockIdx.x;
    const int d0 = blockIdx.y * 16;
    const int b  = blockIdx.z;
    const int t0 = c * CL;
    const int d  = d0 + dl;

#pragma unroll
    for (int i = 0; i < 4; ++i) {
        int f = tid + i * 256;
        int t = f >> 4;
        int e = f & 15;
        size_t row = (size_t)(b * SEQ_LEN + t0 + t);
        sB[t][e]  = dbc[row * 96 + DT_RANK + e];
        sdt[t][e] = dtv[row * D_INNER + d0 + e];
        sx[t][e]  = xc [row * D_INNER + d0 + e];
    }
    __syncthreads();

    const float A = -__expf(A_log[d * 16 + n]);

    float h = 0.f, p = 1.f;
#pragma unroll 4
    for (int t = 0; t < CL; ++t) {
        float dtval = sdt[t][dl];
        float a = __expf(dtval * A);
        h = a * h + (sx[t][dl] * dtval) * sB[t][n];
        p *= a;
    }
    size_t o = (((size_t)(b * NC + c) * D_INNER) + d) * 16 + n;
    hf[o] = h;
    Pf[o] = p;
}

__global__ __launch_bounds__(256) void scan_phaseB(
    const float* __restrict__ hf,
    const float* __restrict__ Pf,
    float* __restrict__ H0)
{
    int idx = blockIdx.x * 256 + threadIdx.x;
    int b  = idx >> 15;
    int dn = idx & 32767;
    float h = 0.f;
#pragma unroll
    for (int c = 0; c < NC; ++c) {
        size_t o = (((size_t)(b * NC + c)) << 15) + dn;
        H0[o] = h;
        h = Pf[o] * h + hf[o];
    }
}

__global__ __launch_bounds__(256) void scan_phaseC(
    const float* __restrict__ dbc,
    const float* __restrict__ dtv,
    const float* __restrict__ xc,
    const float* __restrict__ xz,
    const float* __restrict__ A_log,
    const float* __restrict__ D_skip,
    const float* __restrict__ H0,
    u16* __restrict__ y)              // bf16 out
{
    __shared__ float sB[CL][16];
    __shared__ float sC[CL][16];
    __shared__ float sdt[CL][16];
    __shared__ float sx[CL][16];
    __shared__ float sz[CL][16];

    const int tid = threadIdx.x;
    const int n  = tid & 15;
    const int dl = tid >> 4;
    const int c  = blockIdx.x;
    const int d0 = blockIdx.y * 16;
    const int b  = blockIdx.z;
    const int t0 = c * CL;
    const int d  = d0 + dl;

#pragma unroll
    for (int i = 0; i < 4; ++i) {
        int f = tid + i * 256;
        int t = f >> 4;
        int e = f & 15;
        size_t row = (size_t)(b * SEQ_LEN + t0 + t);
        sB[t][e]  = dbc[row * 96 + DT_RANK + e];
        sC[t][e]  = dbc[row * 96 + DT_RANK + D_STATE + e];
        sdt[t][e] = dtv[row * D_INNER + d0 + e];
        sx[t][e]  = xc [row * D_INNER + d0 + e];
        sz[t][e]  = xz [row * (2 * D_INNER) + D_INNER + d0 + e];
    }
    __syncthreads();

    const float A  = -__expf(A_log[d * 16 + n]);
    const float Dv = D_skip[d];

    float h = H0[(((size_t)(b * NC + c) * D_INNER) + d) * 16 + n];
    u16* yb = y + (size_t)(b * SEQ_LEN + t0) * D_INNER + d;

#pragma unroll 4
    for (int t = 0; t < CL; ++t) {
        float dtval = sdt[t][dl];
        float xv = sx[t][dl];
        float a = __expf(dtval * A);
        h = a * h + (xv * dtval) * sB[t][n];
        float p = sC[t][n] * h;
        p += __shfl_xor(p, 1);
        p += __shfl_xor(p, 2);
        p += __shfl_xor(p, 4);
        p += __shfl_xor(p, 8);
        if (n == 0) {
            float zv = sz[t][dl];
            float sig = 1.f / (1.f + __expf(-zv));
            yb[(size_t)t * D_INNER] = f2bf((p + xv * Dv) * (zv * sig));
        }
    }
}

// ---------------------------------------------------------------------------
// Launch
// ---------------------------------------------------------------------------
extern "C" void kernel_launch(void* const* d_in, const int* in_sizes, int n_in,
                              void* d_out, int out_size, void* d_ws, size_t ws_size,
                              hipStream_t stream)
{
    const float* x      = (const float*)d_in[0];
    const float* W_in   = (const float*)d_in[1];
    const float* conv_w = (const float*)d_in[2];
    const float* conv_b = (const float*)d_in[3];
    const float* W_x    = (const float*)d_in[4];
    const float* W_dt   = (const float*)d_in[5];
    const float* b_dt   = (const float*)d_in[6];
    const float* A_log  = (const float*)d_in[7];
    const float* D_skip = (const float*)d_in[8];
    const float* W_out  = (const float*)d_in[9];
    float* out = (float*)d_out;

    float* ws = (float*)d_ws;
    float* xz    = ws;                                  // 8,388,608 f
    float* xc    = xz + (size_t)8388608;                // 4,194,304 f
    float* dbc   = xc + (size_t)4194304;                //   196,608 f
    float* dtbuf = dbc + (size_t)196608;                // 4,194,304 f
    float* hf    = dtbuf + (size_t)4194304;             // 1,048,576 f
    float* Pf    = hf + (size_t)1048576;
    float* H0    = Pf + (size_t)1048576;
    u16* ybf = (u16*)(H0 + (size_t)1048576);            // 4,194,304 u16
    u16* xbf = ybf + (size_t)4194304;                   // 2,097,152 u16
    u16* wbf = xbf + (size_t)2097152;                   // 4,194,304 u16 (W_in, later W_out)

    // casts for GEMM1
    cast_bf16_kernel<<<2048, 256, 0, stream>>>(x, xbf);       // 2M elems
    cast_bf16_kernel<<<4096, 256, 0, stream>>>(W_in, wbf);    // 4M elems

    // 1. xz = x @ W_in^T (bf16 MFMA): M=2048, N=4096, K=1024
    {
        dim3 grid(4096 / 128, 2048 / 128);
        gemm_bf16_bt<<<grid, 256, 0, stream>>>(xbf, D_MODEL, wbf, D_MODEL,
                                               xz, 2 * D_INNER, D_MODEL);
    }
    // 2. conv + silu
    conv_silu_kernel<<<(T_TOTAL * D_INNER) / 256, 256, 0, stream>>>(xz, conv_w, conv_b, xc);

    // 3. dbc = xc @ W_x^T : M=2048, N=96, K=2048 (fp32)
    {
        dim3 grid((96 + BN - 1) / BN, T_TOTAL / BM);
        gemm_bt<<<grid, 256, 0, stream>>>(xc, D_INNER, W_x, D_INNER,
                                          dbc, 96, T_TOTAL, 96, D_INNER);
    }
    // 4. dt_raw = dbc[:, :64] @ W_dt^T : M=2048, N=2048, K=64 (fp32)
    {
        dim3 grid(D_INNER / BN, T_TOTAL / BM);
        gemm_bt<<<grid, 256, 0, stream>>>(dbc, 96, W_dt, DT_RANK,
                                          dtbuf, D_INNER, T_TOTAL, D_INNER, DT_RANK);
    }
    // 5. softplus
    dt_softplus_kernel<<<(T_TOTAL * D_INNER) / 256, 256, 0, stream>>>(dtbuf, b_dt);

    // 6. chunked selective scan
    {
        dim3 gridA(NC, D_INNER / 16, BATCH);
        scan_phaseA<<<gridA, 256, 0, stream>>>(dbc, dtbuf, xc, A_log, hf, Pf);
        scan_phaseB<<<(BATCH * D_INNER * 16) / 256, 256, 0, stream>>>(hf, Pf, H0);
        scan_phaseC<<<gridA, 256, 0, stream>>>(dbc, dtbuf, xc, xz,
                                               A_log, D_skip, H0, ybf);
    }
    // cast W_out (reuse wbf region; GEMM1 already consumed W_in copy)
    cast_bf16_kernel<<<2048, 256, 0, stream>>>(W_out, wbf);   // 2M elems

    // 7. out = y @ W_out^T (bf16 MFMA): M=2048, N=1024, K=2048
    {
        dim3 grid(1024 / 128, 2048 / 128);
        gemm_bf16_bt<<<grid, 256, 0, stream>>>(ybf, D_INNER, wbf, D_INNER,
                                               out, D_MODEL, D_INNER);
    }
}

// Round 9
// 334.408 us; speedup vs baseline: 6.0285x; 1.7927x over previous
//
#include <hip/hip_runtime.h>
#include <hip/hip_bf16.h>
#include <math.h>

// Problem constants
#define D_MODEL 1024
#define D_STATE 16
#define D_INNER 2048
#define DT_RANK 64
#define BATCH 2
#define SEQ_LEN 1024
#define T_TOTAL (BATCH * SEQ_LEN)   // 2048 rows

// Scan chunking
#define NC 16
#define CL 64

// W_x GEMM split-K
#define KS 16     // k-chunks
#define KC 128    // k per chunk
#define KT 64     // k per LDS stage

typedef unsigned short u16;
typedef __bf16 bf16x8 __attribute__((ext_vector_type(8)));
typedef float f32x4 __attribute__((ext_vector_type(4)));

__device__ __forceinline__ u16 f2bf(float f) {
    unsigned u = __builtin_bit_cast(unsigned, f);
    u += 0x7FFFu + ((u >> 16) & 1u);   // RNE
    return (u16)(u >> 16);
}

#define GLOAD_LDS16(g, l) \
    __builtin_amdgcn_global_load_lds((const __attribute__((address_space(1))) void*)(g), \
                                     (__attribute__((address_space(3))) void*)(l), 16, 0, 0)

// ---------------------------------------------------------------------------
// fp32 -> bf16 cast, 4 floats/thread, packed 8B store. nelem % 1024 == 0.
// ---------------------------------------------------------------------------
__global__ __launch_bounds__(256) void cast_bf16_kernel(
    const float* __restrict__ in, u16* __restrict__ out)
{
    int i = blockIdx.x * 256 + threadIdx.x;
    float4 v = ((const float4*)in)[i];
    unsigned lo = (unsigned)f2bf(v.x) | ((unsigned)f2bf(v.y) << 16);
    unsigned hi = (unsigned)f2bf(v.z) | ((unsigned)f2bf(v.w) << 16);
    ((uint2*)out)[i] = make_uint2(lo, hi);
}

// ---------------------------------------------------------------------------
// bf16 MFMA GEMM (m97 structure): C[m][n] = sum_k A[m][k] * Bw[n][k], fp32 out.
// ---------------------------------------------------------------------------
__global__ __launch_bounds__(256) void gemm_bf16_bt(
    const u16* __restrict__ A, int lda,
    const u16* __restrict__ Bw, int ldb,
    float* __restrict__ C, int ldc, int K)
{
    __shared__ u16 As[128][32];
    __shared__ u16 Bs[128][32];

    const int tid  = threadIdx.x;
    const int lane = tid & 63;
    const int wave = tid >> 6;
    const int wr   = wave >> 1;
    const int wc   = wave & 1;
    const int row0 = blockIdx.y * 128;
    const int col0 = blockIdx.x * 128;

    const int srow = tid >> 2;
    const int scol = (tid & 3) * 8;

    const u16* ag = A  + (size_t)(row0 + srow) * lda + scol;
    const u16* bg = Bw + (size_t)(col0 + srow) * ldb + scol;
    u16* asl = &As[0][0] + wave * 512;
    u16* bsl = &Bs[0][0] + wave * 512;

    f32x4 acc[4][4];
#pragma unroll
    for (int m = 0; m < 4; ++m)
#pragma unroll
        for (int n = 0; n < 4; ++n)
            acc[m][n] = (f32x4){0.f, 0.f, 0.f, 0.f};

    const int fr = lane & 15;
    const int kh = (lane >> 4) * 8;

    for (int k0 = 0; k0 < K; k0 += 32) {
        GLOAD_LDS16(ag + k0,                      asl);
        GLOAD_LDS16(ag + k0 + (size_t)64 * lda,   asl + 2048);
        GLOAD_LDS16(bg + k0,                      bsl);
        GLOAD_LDS16(bg + k0 + (size_t)64 * ldb,   bsl + 2048);
        __syncthreads();

        bf16x8 af[4], bf[4];
#pragma unroll
        for (int m = 0; m < 4; ++m)
            af[m] = *(const bf16x8*)&As[wr * 64 + m * 16 + fr][kh];
#pragma unroll
        for (int n = 0; n < 4; ++n)
            bf[n] = *(const bf16x8*)&Bs[wc * 64 + n * 16 + fr][kh];
#pragma unroll
        for (int m = 0; m < 4; ++m)
#pragma unroll
            for (int n = 0; n < 4; ++n)
                acc[m][n] = __builtin_amdgcn_mfma_f32_16x16x32_bf16(
                    af[m], bf[n], acc[m][n], 0, 0, 0);
        __syncthreads();
    }

    const int crow = (lane >> 4) * 4;
#pragma unroll
    for (int m = 0; m < 4; ++m) {
        const int gr = row0 + wr * 64 + m * 16 + crow;
#pragma unroll
        for (int n = 0; n < 4; ++n) {
            const int gc = col0 + wc * 64 + n * 16 + fr;
#pragma unroll
            for (int r = 0; r < 4; ++r)
                C[(size_t)(gr + r) * ldc + gc] = acc[m][n][r];
        }
    }
}

// ---------------------------------------------------------------------------
// Split-K fp32 GEMM for dbc = xc @ W_x^T (M=2048, N=96, K=2048).
// Grid (KS, M/32) = 1024 blocks. Each block: 32 rows x 96 cols over KC=128 k.
// ---------------------------------------------------------------------------
__global__ __launch_bounds__(256) void wx_partial(
    const float* __restrict__ A,    // xc [T_TOTAL][D_INNER]
    const float* __restrict__ Bw,   // W_x [96][D_INNER]
    float* __restrict__ part)       // [KS][T_TOTAL][96]
{
    __shared__ float As[32][68];    // [m][k]
    __shared__ float Bs[KT][98];    // [k][n] transposed

    const int tid = threadIdx.x;
    const int ks  = blockIdx.x;
    const int m0  = blockIdx.y * 32;
    const int k0  = ks * KC;

    const int tx = tid & 15;
    const int ty = tid >> 4;

    float acc[2][6] = {};

    for (int kk = 0; kk < KC; kk += KT) {
#pragma unroll
        for (int i = 0; i < 2; ++i) {
            int slot = tid + i * 256;
            int m  = slot >> 4;
            int kq = slot & 15;
            float4 v = *(const float4*)&A[(size_t)(m0 + m) * D_INNER + k0 + kk + kq * 4];
            *(float4*)&As[m][kq * 4] = v;
        }
#pragma unroll
        for (int i = 0; i < 6; ++i) {
            int slot = tid + i * 256;
            int n  = slot >> 4;
            int kq = slot & 15;
            float4 v = *(const float4*)&Bw[(size_t)n * D_INNER + k0 + kk + kq * 4];
            Bs[kq * 4 + 0][n] = v.x;
            Bs[kq * 4 + 1][n] = v.y;
            Bs[kq * 4 + 2][n] = v.z;
            Bs[kq * 4 + 3][n] = v.w;
        }
        __syncthreads();

#pragma unroll 8
        for (int k = 0; k < KT; ++k) {
            float a0 = As[ty * 2 + 0][k];
            float a1 = As[ty * 2 + 1][k];
            float2 b0 = *(const float2*)&Bs[k][tx * 6 + 0];
            float2 b1 = *(const float2*)&Bs[k][tx * 6 + 2];
            float2 b2 = *(const float2*)&Bs[k][tx * 6 + 4];
            float bv[6] = {b0.x, b0.y, b1.x, b1.y, b2.x, b2.y};
#pragma unroll
            for (int j = 0; j < 6; ++j) {
                acc[0][j] += a0 * bv[j];
                acc[1][j] += a1 * bv[j];
            }
        }
        __syncthreads();
    }

#pragma unroll
    for (int i = 0; i < 2; ++i) {
        size_t base = ((size_t)ks * T_TOTAL + (m0 + ty * 2 + i)) * 96 + tx * 6;
#pragma unroll
        for (int j = 0; j < 6; ++j)
            part[base + j] = acc[i][j];
    }
}

__global__ __launch_bounds__(256) void wx_reduce(
    const float* __restrict__ part, float* __restrict__ dbc)
{
    int i = blockIdx.x * 256 + threadIdx.x;
    float s = 0.f;
#pragma unroll
    for (int ks = 0; ks < KS; ++ks)
        s += part[(size_t)ks * T_TOTAL * 96 + i];
    dbc[i] = s;
}

// ---------------------------------------------------------------------------
// dt GEMM + fused bias+softplus:
// dtb[m][n] = softplus( sum_k dbc[m][k<64] * W_dt[n][k] + b_dt[n] )
// M=T_TOTAL, N=D_INNER, K=64 (=DT_RANK). lda=96, ldb=64, ldc=D_INNER.
// 64x64 tile, 16x16 threads x 4x4 acc.
// ---------------------------------------------------------------------------
__global__ __launch_bounds__(256) void dt_gemm(
    const float* __restrict__ A,    // dbc [T_TOTAL][96]
    const float* __restrict__ Bw,   // W_dt [D_INNER][64]
    const float* __restrict__ bdt,  // [D_INNER]
    float* __restrict__ dtb)        // [T_TOTAL][D_INNER]
{
    __shared__ float As[16][65];
    __shared__ float Bs[16][65];

    const int tid = threadIdx.x;
    const int row0 = blockIdx.y * 64;
    const int col0 = blockIdx.x * 64;
    const int ty = tid >> 4;
    const int tx = tid & 15;

    float acc[4][4] = {};

    for (int k0 = 0; k0 < DT_RANK; k0 += 16) {
#pragma unroll
        for (int i = 0; i < 4; ++i) {
            int idx = tid + i * 256;
            int m = idx >> 4;
            int k = idx & 15;
            As[k][m] = A[(size_t)(row0 + m) * 96 + (k0 + k)];
        }
#pragma unroll
        for (int i = 0; i < 4; ++i) {
            int idx = tid + i * 256;
            int n = idx >> 4;
            int k = idx & 15;
            Bs[k][n] = Bw[(size_t)(col0 + n) * DT_RANK + (k0 + k)];
        }
        __syncthreads();

#pragma unroll
        for (int k = 0; k < 16; ++k) {
            float a[4], b[4];
#pragma unroll
            for (int i = 0; i < 4; ++i) a[i] = As[k][ty * 4 + i];
#pragma unroll
            for (int j = 0; j < 4; ++j) b[j] = Bs[k][tx * 4 + j];
#pragma unroll
            for (int i = 0; i < 4; ++i)
#pragma unroll
                for (int j = 0; j < 4; ++j)
                    acc[i][j] += a[i] * b[j];
        }
        __syncthreads();
    }

#pragma unroll
    for (int i = 0; i < 4; ++i) {
        int gm = row0 + ty * 4 + i;
#pragma unroll
        for (int j = 0; j < 4; ++j) {
            int gn = col0 + tx * 4 + j;
            float xv = acc[i][j] + bdt[gn];
            float sp = (xv > 20.f) ? xv : log1pf(__expf(xv));
            dtb[(size_t)gm * D_INNER + gn] = sp;
        }
    }
}

// ---------------------------------------------------------------------------
// Causal depthwise conv (K=4) + bias + SiLU.
// ---------------------------------------------------------------------------
__global__ __launch_bounds__(256) void conv_silu_kernel(
    const float* __restrict__ xz,
    const float* __restrict__ cw,
    const float* __restrict__ cb,
    float* __restrict__ xc)
{
    int idx = blockIdx.x * 256 + threadIdx.x;
    int d = idx & (D_INNER - 1);
    int t = (idx >> 11) & (SEQ_LEN - 1);
    int b = idx >> 21;

    const float* base = xz + ((size_t)b * SEQ_LEN + t) * (2 * D_INNER) + d;
    float w0 = cw[d * 4 + 0], w1 = cw[d * 4 + 1], w2 = cw[d * 4 + 2], w3 = cw[d * 4 + 3];
    float acc = cb[d];
    if (t >= 3) acc += w0 * base[-3 * (2 * D_INNER)];
    if (t >= 2) acc += w1 * base[-2 * (2 * D_INNER)];
    if (t >= 1) acc += w2 * base[-1 * (2 * D_INNER)];
    acc += w3 * base[0];
    float s = acc / (1.f + __expf(-acc));
    xc[idx] = s;
}

// ---------------------------------------------------------------------------
// Chunked selective scan
// ---------------------------------------------------------------------------
__global__ __launch_bounds__(256) void scan_phaseA(
    const float* __restrict__ dbc,
    const float* __restrict__ dtv,
    const float* __restrict__ xc,
    const float* __restrict__ A_log,
    float* __restrict__ hf,
    float* __restrict__ Pf)
{
    __shared__ float sB[CL][16];
    __shared__ float sdt[CL][16];
    __shared__ float sx[CL][16];

    const int tid = threadIdx.x;
    const int n  = tid & 15;
    const int dl = tid >> 4;
    const int c  = blockIdx.x;
    const int d0 = blockIdx.y * 16;
    const int b  = blockIdx.z;
    const int t0 = c * CL;
    const int d  = d0 + dl;

#pragma unroll
    for (int i = 0; i < 4; ++i) {
        int f = tid + i * 256;
        int t = f >> 4;
        int e = f & 15;
        size_t row = (size_t)(b * SEQ_LEN + t0 + t);
        sB[t][e]  = dbc[row * 96 + DT_RANK + e];
        sdt[t][e] = dtv[row * D_INNER + d0 + e];
        sx[t][e]  = xc [row * D_INNER + d0 + e];
    }
    __syncthreads();

    const float A = -__expf(A_log[d * 16 + n]);

    float h = 0.f, p = 1.f;
#pragma unroll 4
    for (int t = 0; t < CL; ++t) {
        float dtval = sdt[t][dl];
        float a = __expf(dtval * A);
        h = a * h + (sx[t][dl] * dtval) * sB[t][n];
        p *= a;
    }
    size_t o = (((size_t)(b * NC + c) * D_INNER) + d) * 16 + n;
    hf[o] = h;
    Pf[o] = p;
}

__global__ __launch_bounds__(256) void scan_phaseB(
    const float* __restrict__ hf,
    const float* __restrict__ Pf,
    float* __restrict__ H0)
{
    int idx = blockIdx.x * 256 + threadIdx.x;
    int b  = idx >> 15;
    int dn = idx & 32767;
    float h = 0.f;
#pragma unroll
    for (int c = 0; c < NC; ++c) {
        size_t o = (((size_t)(b * NC + c)) << 15) + dn;
        H0[o] = h;
        h = Pf[o] * h + hf[o];
    }
}

__global__ __launch_bounds__(256) void scan_phaseC(
    const float* __restrict__ dbc,
    const float* __restrict__ dtv,
    const float* __restrict__ xc,
    const float* __restrict__ xz,
    const float* __restrict__ A_log,
    const float* __restrict__ D_skip,
    const float* __restrict__ H0,
    u16* __restrict__ y)              // bf16 out
{
    __shared__ float sB[CL][16];
    __shared__ float sC[CL][16];
    __shared__ float sdt[CL][16];
    __shared__ float sx[CL][16];
    __shared__ float sz[CL][16];

    const int tid = threadIdx.x;
    const int n  = tid & 15;
    const int dl = tid >> 4;
    const int c  = blockIdx.x;
    const int d0 = blockIdx.y * 16;
    const int b  = blockIdx.z;
    const int t0 = c * CL;
    const int d  = d0 + dl;

#pragma unroll
    for (int i = 0; i < 4; ++i) {
        int f = tid + i * 256;
        int t = f >> 4;
        int e = f & 15;
        size_t row = (size_t)(b * SEQ_LEN + t0 + t);
        sB[t][e]  = dbc[row * 96 + DT_RANK + e];
        sC[t][e]  = dbc[row * 96 + DT_RANK + D_STATE + e];
        sdt[t][e] = dtv[row * D_INNER + d0 + e];
        sx[t][e]  = xc [row * D_INNER + d0 + e];
        sz[t][e]  = xz [row * (2 * D_INNER) + D_INNER + d0 + e];
    }
    __syncthreads();

    const float A  = -__expf(A_log[d * 16 + n]);
    const float Dv = D_skip[d];

    float h = H0[(((size_t)(b * NC + c) * D_INNER) + d) * 16 + n];
    u16* yb = y + (size_t)(b * SEQ_LEN + t0) * D_INNER + d;

#pragma unroll 4
    for (int t = 0; t < CL; ++t) {
        float dtval = sdt[t][dl];
        float xv = sx[t][dl];
        float a = __expf(dtval * A);
        h = a * h + (xv * dtval) * sB[t][n];
        float p = sC[t][n] * h;
        p += __shfl_xor(p, 1);
        p += __shfl_xor(p, 2);
        p += __shfl_xor(p, 4);
        p += __shfl_xor(p, 8);
        if (n == 0) {
            float zv = sz[t][dl];
            float sig = 1.f / (1.f + __expf(-zv));
            yb[(size_t)t * D_INNER] = f2bf((p + xv * Dv) * (zv * sig));
        }
    }
}

// ---------------------------------------------------------------------------
// Launch
// ---------------------------------------------------------------------------
extern "C" void kernel_launch(void* const* d_in, const int* in_sizes, int n_in,
                              void* d_out, int out_size, void* d_ws, size_t ws_size,
                              hipStream_t stream)
{
    const float* x      = (const float*)d_in[0];
    const float* W_in   = (const float*)d_in[1];
    const float* conv_w = (const float*)d_in[2];
    const float* conv_b = (const float*)d_in[3];
    const float* W_x    = (const float*)d_in[4];
    const float* W_dt   = (const float*)d_in[5];
    const float* b_dt   = (const float*)d_in[6];
    const float* A_log  = (const float*)d_in[7];
    const float* D_skip = (const float*)d_in[8];
    const float* W_out  = (const float*)d_in[9];
    float* out = (float*)d_out;

    float* ws = (float*)d_ws;
    float* xz    = ws;                                  // 8,388,608 f
    float* xc    = xz + (size_t)8388608;                // 4,194,304 f
    float* dbc   = xc + (size_t)4194304;                //   196,608 f
    float* dtbuf = dbc + (size_t)196608;                // 4,194,304 f
    float* hf    = dtbuf + (size_t)4194304;             // 1,048,576 f
    float* Pf    = hf + (size_t)1048576;
    float* H0    = Pf + (size_t)1048576;
    u16* ybf = (u16*)(H0 + (size_t)1048576);            // 4,194,304 u16
    u16* xbf = ybf + (size_t)4194304;                   // 2,097,152 u16
    u16* wbf = xbf + (size_t)2097152;                   // 4,194,304 u16
    // split-K partials alias dtbuf (12.6 MB <= 16.8 MB); consumed by wx_reduce
    // before dt_gemm overwrites dtbuf (stream-ordered).
    float* part = dtbuf;

    // casts for GEMM1
    cast_bf16_kernel<<<2048, 256, 0, stream>>>(x, xbf);
    cast_bf16_kernel<<<4096, 256, 0, stream>>>(W_in, wbf);

    // 1. xz = x @ W_in^T (bf16 MFMA): M=2048, N=4096, K=1024
    {
        dim3 grid(4096 / 128, 2048 / 128);
        gemm_bf16_bt<<<grid, 256, 0, stream>>>(xbf, D_MODEL, wbf, D_MODEL,
                                               xz, 2 * D_INNER, D_MODEL);
    }
    // 2. conv + silu
    conv_silu_kernel<<<(T_TOTAL * D_INNER) / 256, 256, 0, stream>>>(xz, conv_w, conv_b, xc);

    // 3. dbc = xc @ W_x^T : split-K fp32
    {
        dim3 grid(KS, T_TOTAL / 32);
        wx_partial<<<grid, 256, 0, stream>>>(xc, W_x, part);
        wx_reduce<<<(T_TOTAL * 96) / 256, 256, 0, stream>>>(part, dbc);
    }
    // 4+5. dt = softplus(dbc[:, :64] @ W_dt^T + b_dt)  (fused)
    {
        dim3 grid(D_INNER / 64, T_TOTAL / 64);
        dt_gemm<<<grid, 256, 0, stream>>>(dbc, W_dt, b_dt, dtbuf);
    }
    // 6. chunked selective scan
    {
        dim3 gridA(NC, D_INNER / 16, BATCH);
        scan_phaseA<<<gridA, 256, 0, stream>>>(dbc, dtbuf, xc, A_log, hf, Pf);
        scan_phaseB<<<(BATCH * D_INNER * 16) / 256, 256, 0, stream>>>(hf, Pf, H0);
        scan_phaseC<<<gridA, 256, 0, stream>>>(dbc, dtbuf, xc, xz,
                                               A_log, D_skip, H0, ybf);
    }
    // cast W_out (reuse wbf region)
    cast_bf16_kernel<<<2048, 256, 0, stream>>>(W_out, wbf);

    // 7. out = y @ W_out^T (bf16 MFMA): M=2048, N=1024, K=2048
    {
        dim3 grid(1024 / 128, 2048 / 128);
        gemm_bf16_bt<<<grid, 256, 0, stream>>>(ybf, D_INNER, wbf, D_INNER,
                                               out, D_MODEL, D_INNER);
    }
}

// Round 10
// 290.933 us; speedup vs baseline: 6.9293x; 1.1494x over previous
//
#include <hip/hip_runtime.h>
#include <hip/hip_bf16.h>
#include <math.h>

// Problem constants
#define D_MODEL 1024
#define D_STATE 16
#define D_INNER 2048
#define DT_RANK 64
#define BATCH 2
#define SEQ_LEN 1024
#define T_TOTAL (BATCH * SEQ_LEN)   // 2048 rows

// Scan chunking: h[16] per thread, one thread per (b, chunk, d)
#define NC 64
#define CL 16

// W_x GEMM split-K
#define KS 16     // k-chunks
#define KC 128    // k per chunk
#define KT 64     // k per LDS stage

typedef unsigned short u16;
typedef __bf16 bf16x8 __attribute__((ext_vector_type(8)));
typedef float f32x4 __attribute__((ext_vector_type(4)));

__device__ __forceinline__ u16 f2bf(float f) {
    unsigned u = __builtin_bit_cast(unsigned, f);
    u += 0x7FFFu + ((u >> 16) & 1u);   // RNE
    return (u16)(u >> 16);
}

#define GLOAD_LDS16(g, l) \
    __builtin_amdgcn_global_load_lds((const __attribute__((address_space(1))) void*)(g), \
                                     (__attribute__((address_space(3))) void*)(l), 16, 0, 0)

// ---------------------------------------------------------------------------
// fp32 -> bf16 cast, 4 floats/thread, packed 8B store. nelem % 1024 == 0.
// ---------------------------------------------------------------------------
__global__ __launch_bounds__(256) void cast_bf16_kernel(
    const float* __restrict__ in, u16* __restrict__ out)
{
    int i = blockIdx.x * 256 + threadIdx.x;
    float4 v = ((const float4*)in)[i];
    unsigned lo = (unsigned)f2bf(v.x) | ((unsigned)f2bf(v.y) << 16);
    unsigned hi = (unsigned)f2bf(v.z) | ((unsigned)f2bf(v.w) << 16);
    ((uint2*)out)[i] = make_uint2(lo, hi);
}

// ---------------------------------------------------------------------------
// bf16 MFMA GEMM (m97 structure): C[m][n] = sum_k A[m][k] * Bw[n][k], fp32 out.
// ---------------------------------------------------------------------------
__global__ __launch_bounds__(256) void gemm_bf16_bt(
    const u16* __restrict__ A, int lda,
    const u16* __restrict__ Bw, int ldb,
    float* __restrict__ C, int ldc, int K)
{
    __shared__ u16 As[128][32];
    __shared__ u16 Bs[128][32];

    const int tid  = threadIdx.x;
    const int lane = tid & 63;
    const int wave = tid >> 6;
    const int wr   = wave >> 1;
    const int wc   = wave & 1;
    const int row0 = blockIdx.y * 128;
    const int col0 = blockIdx.x * 128;

    const int srow = tid >> 2;
    const int scol = (tid & 3) * 8;

    const u16* ag = A  + (size_t)(row0 + srow) * lda + scol;
    const u16* bg = Bw + (size_t)(col0 + srow) * ldb + scol;
    u16* asl = &As[0][0] + wave * 512;
    u16* bsl = &Bs[0][0] + wave * 512;

    f32x4 acc[4][4];
#pragma unroll
    for (int m = 0; m < 4; ++m)
#pragma unroll
        for (int n = 0; n < 4; ++n)
            acc[m][n] = (f32x4){0.f, 0.f, 0.f, 0.f};

    const int fr = lane & 15;
    const int kh = (lane >> 4) * 8;

    for (int k0 = 0; k0 < K; k0 += 32) {
        GLOAD_LDS16(ag + k0,                      asl);
        GLOAD_LDS16(ag + k0 + (size_t)64 * lda,   asl + 2048);
        GLOAD_LDS16(bg + k0,                      bsl);
        GLOAD_LDS16(bg + k0 + (size_t)64 * ldb,   bsl + 2048);
        __syncthreads();

        bf16x8 af[4], bf[4];
#pragma unroll
        for (int m = 0; m < 4; ++m)
            af[m] = *(const bf16x8*)&As[wr * 64 + m * 16 + fr][kh];
#pragma unroll
        for (int n = 0; n < 4; ++n)
            bf[n] = *(const bf16x8*)&Bs[wc * 64 + n * 16 + fr][kh];
#pragma unroll
        for (int m = 0; m < 4; ++m)
#pragma unroll
            for (int n = 0; n < 4; ++n)
                acc[m][n] = __builtin_amdgcn_mfma_f32_16x16x32_bf16(
                    af[m], bf[n], acc[m][n], 0, 0, 0);
        __syncthreads();
    }

    const int crow = (lane >> 4) * 4;
#pragma unroll
    for (int m = 0; m < 4; ++m) {
        const int gr = row0 + wr * 64 + m * 16 + crow;
#pragma unroll
        for (int n = 0; n < 4; ++n) {
            const int gc = col0 + wc * 64 + n * 16 + fr;
#pragma unroll
            for (int r = 0; r < 4; ++r)
                C[(size_t)(gr + r) * ldc + gc] = acc[m][n][r];
        }
    }
}

// ---------------------------------------------------------------------------
// Split-K fp32 GEMM for dbc = xc @ W_x^T (M=2048, N=96, K=2048).
// ---------------------------------------------------------------------------
__global__ __launch_bounds__(256) void wx_partial(
    const float* __restrict__ A,    // xc [T_TOTAL][D_INNER]
    const float* __restrict__ Bw,   // W_x [96][D_INNER]
    float* __restrict__ part)       // [KS][T_TOTAL][96]
{
    __shared__ float As[32][68];
    __shared__ float Bs[KT][98];

    const int tid = threadIdx.x;
    const int ks  = blockIdx.x;
    const int m0  = blockIdx.y * 32;
    const int k0  = ks * KC;

    const int tx = tid & 15;
    const int ty = tid >> 4;

    float acc[2][6] = {};

    for (int kk = 0; kk < KC; kk += KT) {
#pragma unroll
        for (int i = 0; i < 2; ++i) {
            int slot = tid + i * 256;
            int m  = slot >> 4;
            int kq = slot & 15;
            float4 v = *(const float4*)&A[(size_t)(m0 + m) * D_INNER + k0 + kk + kq * 4];
            *(float4*)&As[m][kq * 4] = v;
        }
#pragma unroll
        for (int i = 0; i < 6; ++i) {
            int slot = tid + i * 256;
            int n  = slot >> 4;
            int kq = slot & 15;
            float4 v = *(const float4*)&Bw[(size_t)n * D_INNER + k0 + kk + kq * 4];
            Bs[kq * 4 + 0][n] = v.x;
            Bs[kq * 4 + 1][n] = v.y;
            Bs[kq * 4 + 2][n] = v.z;
            Bs[kq * 4 + 3][n] = v.w;
        }
        __syncthreads();

#pragma unroll 8
        for (int k = 0; k < KT; ++k) {
            float a0 = As[ty * 2 + 0][k];
            float a1 = As[ty * 2 + 1][k];
            float2 b0 = *(const float2*)&Bs[k][tx * 6 + 0];
            float2 b1 = *(const float2*)&Bs[k][tx * 6 + 2];
            float2 b2 = *(const float2*)&Bs[k][tx * 6 + 4];
            float bv[6] = {b0.x, b0.y, b1.x, b1.y, b2.x, b2.y};
#pragma unroll
            for (int j = 0; j < 6; ++j) {
                acc[0][j] += a0 * bv[j];
                acc[1][j] += a1 * bv[j];
            }
        }
        __syncthreads();
    }

#pragma unroll
    for (int i = 0; i < 2; ++i) {
        size_t base = ((size_t)ks * T_TOTAL + (m0 + ty * 2 + i)) * 96 + tx * 6;
#pragma unroll
        for (int j = 0; j < 6; ++j)
            part[base + j] = acc[i][j];
    }
}

__global__ __launch_bounds__(256) void wx_reduce(
    const float* __restrict__ part, float* __restrict__ dbc)
{
    int i = blockIdx.x * 256 + threadIdx.x;
    float s = 0.f;
#pragma unroll
    for (int ks = 0; ks < KS; ++ks)
        s += part[(size_t)ks * T_TOTAL * 96 + i];
    dbc[i] = s;
}

// ---------------------------------------------------------------------------
// dt GEMM + fused bias+softplus.
// ---------------------------------------------------------------------------
__global__ __launch_bounds__(256) void dt_gemm(
    const float* __restrict__ A,    // dbc [T_TOTAL][96]
    const float* __restrict__ Bw,   // W_dt [D_INNER][64]
    const float* __restrict__ bdt,  // [D_INNER]
    float* __restrict__ dtb)        // [T_TOTAL][D_INNER]
{
    __shared__ float As[16][65];
    __shared__ float Bs[16][65];

    const int tid = threadIdx.x;
    const int row0 = blockIdx.y * 64;
    const int col0 = blockIdx.x * 64;
    const int ty = tid >> 4;
    const int tx = tid & 15;

    float acc[4][4] = {};

    for (int k0 = 0; k0 < DT_RANK; k0 += 16) {
#pragma unroll
        for (int i = 0; i < 4; ++i) {
            int idx = tid + i * 256;
            int m = idx >> 4;
            int k = idx & 15;
            As[k][m] = A[(size_t)(row0 + m) * 96 + (k0 + k)];
        }
#pragma unroll
        for (int i = 0; i < 4; ++i) {
            int idx = tid + i * 256;
            int n = idx >> 4;
            int k = idx & 15;
            Bs[k][n] = Bw[(size_t)(col0 + n) * DT_RANK + (k0 + k)];
        }
        __syncthreads();

#pragma unroll
        for (int k = 0; k < 16; ++k) {
            float a[4], b[4];
#pragma unroll
            for (int i = 0; i < 4; ++i) a[i] = As[k][ty * 4 + i];
#pragma unroll
            for (int j = 0; j < 4; ++j) b[j] = Bs[k][tx * 4 + j];
#pragma unroll
            for (int i = 0; i < 4; ++i)
#pragma unroll
                for (int j = 0; j < 4; ++j)
                    acc[i][j] += a[i] * b[j];
        }
        __syncthreads();
    }

#pragma unroll
    for (int i = 0; i < 4; ++i) {
        int gm = row0 + ty * 4 + i;
#pragma unroll
        for (int j = 0; j < 4; ++j) {
            int gn = col0 + tx * 4 + j;
            float xv = acc[i][j] + bdt[gn];
            float sp = (xv > 20.f) ? xv : log1pf(__expf(xv));
            dtb[(size_t)gm * D_INNER + gn] = sp;
        }
    }
}

// ---------------------------------------------------------------------------
// Causal depthwise conv (K=4) + bias + SiLU.
// ---------------------------------------------------------------------------
__global__ __launch_bounds__(256) void conv_silu_kernel(
    const float* __restrict__ xz,
    const float* __restrict__ cw,
    const float* __restrict__ cb,
    float* __restrict__ xc)
{
    int idx = blockIdx.x * 256 + threadIdx.x;
    int d = idx & (D_INNER - 1);
    int t = (idx >> 11) & (SEQ_LEN - 1);
    int b = idx >> 21;

    const float* base = xz + ((size_t)b * SEQ_LEN + t) * (2 * D_INNER) + d;
    float w0 = cw[d * 4 + 0], w1 = cw[d * 4 + 1], w2 = cw[d * 4 + 2], w3 = cw[d * 4 + 3];
    float acc = cb[d];
    if (t >= 3) acc += w0 * base[-3 * (2 * D_INNER)];
    if (t >= 2) acc += w1 * base[-2 * (2 * D_INNER)];
    if (t >= 1) acc += w2 * base[-1 * (2 * D_INNER)];
    acc += w3 * base[0];
    float s = acc / (1.f + __expf(-acc));
    xc[idx] = s;
}

// ---------------------------------------------------------------------------
// Chunked selective scan, h[16]-in-registers.
// One thread per (b, chunk, d). Grid (NC, D_INNER/256, BATCH), 256 thr.
// Phase A: local scan from 0 -> hbuf[b][c][n][d] (chunk-final) + sdt (sum dt).
// Phase B: serial over chunks per (b,n,d); P = exp(A*sdt); hbuf -> H0 in place.
// Phase C: re-run from H0, y = sum_n C*h, fused epilogue, bf16 out.
// ---------------------------------------------------------------------------
__global__ __launch_bounds__(256) void scanA(
    const float* __restrict__ dbc,
    const float* __restrict__ dtv,
    const float* __restrict__ xc,
    const float* __restrict__ A_log,
    float* __restrict__ hbuf,         // [B][NC][16][D_INNER]
    float* __restrict__ sdt)          // [B][NC][D_INNER]
{
    __shared__ float sB[CL][16];

    const int tid = threadIdx.x;
    const int c = blockIdx.x;
    const int b = blockIdx.z;
    const int d = blockIdx.y * 256 + tid;
    const int t0 = c * CL;

    {
        int t = tid >> 4, e = tid & 15;
        sB[t][e] = dbc[(size_t)(b * SEQ_LEN + t0 + t) * 96 + DT_RANK + e];
    }

    float A[16];
#pragma unroll
    for (int i = 0; i < 4; ++i) {
        float4 v = *(const float4*)&A_log[d * 16 + i * 4];
        A[i * 4 + 0] = -__expf(v.x);
        A[i * 4 + 1] = -__expf(v.y);
        A[i * 4 + 2] = -__expf(v.z);
        A[i * 4 + 3] = -__expf(v.w);
    }
    __syncthreads();

    float h[16];
#pragma unroll
    for (int n = 0; n < 16; ++n) h[n] = 0.f;
    float sum = 0.f;

#pragma unroll 4
    for (int t = 0; t < CL; ++t) {
        size_t row = (size_t)(b * SEQ_LEN + t0 + t);
        float dtval = dtv[row * D_INNER + d];
        float xv    = xc [row * D_INNER + d];
        float w = xv * dtval;
        sum += dtval;
#pragma unroll
        for (int n = 0; n < 16; ++n) {
            float a = __expf(dtval * A[n]);
            h[n] = a * h[n] + w * sB[t][n];
        }
    }

    size_t o = (size_t)(b * NC + c) * 16 * D_INNER + d;
#pragma unroll
    for (int n = 0; n < 16; ++n)
        hbuf[o + (size_t)n * D_INNER] = h[n];
    sdt[(size_t)(b * NC + c) * D_INNER + d] = sum;
}

__global__ __launch_bounds__(256) void scanB(
    const float* __restrict__ A_log,
    const float* __restrict__ sdt,
    float* __restrict__ hbuf)         // in: chunk-final; out: chunk-initial H0
{
    int idx = blockIdx.x * 256 + threadIdx.x;   // b*(16*D_INNER) + n*D_INNER + d
    int b  = idx >> 15;
    int nd = idx & 32767;
    int n  = nd >> 11;
    int d  = nd & (D_INNER - 1);

    const float A = -__expf(A_log[d * 16 + n]);
    float h = 0.f;
#pragma unroll 8
    for (int c = 0; c < NC; ++c) {
        size_t o = ((size_t)(b * NC + c) * 16 + n) * D_INNER + d;
        float tmp = hbuf[o];
        float P = __expf(A * sdt[(size_t)(b * NC + c) * D_INNER + d]);
        hbuf[o] = h;
        h = P * h + tmp;
    }
}

__global__ __launch_bounds__(256) void scanC(
    const float* __restrict__ dbc,
    const float* __restrict__ dtv,
    const float* __restrict__ xc,
    const float* __restrict__ xz,
    const float* __restrict__ A_log,
    const float* __restrict__ D_skip,
    const float* __restrict__ hbuf,   // H0
    u16* __restrict__ y)              // bf16 out
{
    __shared__ float sB[CL][16];
    __shared__ float sC[CL][16];

    const int tid = threadIdx.x;
    const int c = blockIdx.x;
    const int b = blockIdx.z;
    const int d = blockIdx.y * 256 + tid;
    const int t0 = c * CL;

    {
        int t = tid >> 4, e = tid & 15;
        size_t row = (size_t)(b * SEQ_LEN + t0 + t);
        sB[t][e] = dbc[row * 96 + DT_RANK + e];
        sC[t][e] = dbc[row * 96 + DT_RANK + D_STATE + e];
    }

    float A[16];
#pragma unroll
    for (int i = 0; i < 4; ++i) {
        float4 v = *(const float4*)&A_log[d * 16 + i * 4];
        A[i * 4 + 0] = -__expf(v.x);
        A[i * 4 + 1] = -__expf(v.y);
        A[i * 4 + 2] = -__expf(v.z);
        A[i * 4 + 3] = -__expf(v.w);
    }
    const float Dv = D_skip[d];

    float h[16];
    size_t ho = (size_t)(b * NC + c) * 16 * D_INNER + d;
#pragma unroll
    for (int n = 0; n < 16; ++n)
        h[n] = hbuf[ho + (size_t)n * D_INNER];
    __syncthreads();

#pragma unroll 4
    for (int t = 0; t < CL; ++t) {
        size_t row = (size_t)(b * SEQ_LEN + t0 + t);
        float dtval = dtv[row * D_INNER + d];
        float xv    = xc [row * D_INNER + d];
        float zv    = xz [row * (2 * D_INNER) + D_INNER + d];
        float w = xv * dtval;
        float yv = 0.f;
#pragma unroll
        for (int n = 0; n < 16; ++n) {
            float a = __expf(dtval * A[n]);
            h[n] = a * h[n] + w * sB[t][n];
            yv += sC[t][n] * h[n];
        }
        float sig = 1.f / (1.f + __expf(-zv));
        y[row * D_INNER + d] = f2bf((yv + xv * Dv) * (zv * sig));
    }
}

// ---------------------------------------------------------------------------
// Launch
// ---------------------------------------------------------------------------
extern "C" void kernel_launch(void* const* d_in, const int* in_sizes, int n_in,
                              void* d_out, int out_size, void* d_ws, size_t ws_size,
                              hipStream_t stream)
{
    const float* x      = (const float*)d_in[0];
    const float* W_in   = (const float*)d_in[1];
    const float* conv_w = (const float*)d_in[2];
    const float* conv_b = (const float*)d_in[3];
    const float* W_x    = (const float*)d_in[4];
    const float* W_dt   = (const float*)d_in[5];
    const float* b_dt   = (const float*)d_in[6];
    const float* A_log  = (const float*)d_in[7];
    const float* D_skip = (const float*)d_in[8];
    const float* W_out  = (const float*)d_in[9];
    float* out = (float*)d_out;

    float* ws = (float*)d_ws;
    float* xz    = ws;                                  // 8,388,608 f
    float* xc    = xz + (size_t)8388608;                // 4,194,304 f
    float* dbc   = xc + (size_t)4194304;                //   196,608 f
    float* dtbuf = dbc + (size_t)196608;                // 4,194,304 f
    float* hbuf  = dtbuf + (size_t)4194304;             // 4,194,304 f (B*NC*16*D_INNER)
    float* sdt   = hbuf + (size_t)4194304;              //   262,144 f
    u16* ybf = (u16*)(sdt + (size_t)262144);            // 4,194,304 u16
    u16* xbf = ybf + (size_t)4194304;                   // 2,097,152 u16
    u16* wbf = xbf + (size_t)2097152;                   // 4,194,304 u16
    // split-K partials alias dtbuf (12.6 MB <= 16.8 MB); consumed by wx_reduce
    // before dt_gemm overwrites dtbuf (stream-ordered).
    float* part = dtbuf;

    // casts for GEMM1
    cast_bf16_kernel<<<2048, 256, 0, stream>>>(x, xbf);
    cast_bf16_kernel<<<4096, 256, 0, stream>>>(W_in, wbf);

    // 1. xz = x @ W_in^T (bf16 MFMA): M=2048, N=4096, K=1024
    {
        dim3 grid(4096 / 128, 2048 / 128);
        gemm_bf16_bt<<<grid, 256, 0, stream>>>(xbf, D_MODEL, wbf, D_MODEL,
                                               xz, 2 * D_INNER, D_MODEL);
    }
    // 2. conv + silu
    conv_silu_kernel<<<(T_TOTAL * D_INNER) / 256, 256, 0, stream>>>(xz, conv_w, conv_b, xc);

    // 3. dbc = xc @ W_x^T : split-K fp32
    {
        dim3 grid(KS, T_TOTAL / 32);
        wx_partial<<<grid, 256, 0, stream>>>(xc, W_x, part);
        wx_reduce<<<(T_TOTAL * 96) / 256, 256, 0, stream>>>(part, dbc);
    }
    // 4+5. dt = softplus(dbc[:, :64] @ W_dt^T + b_dt)  (fused)
    {
        dim3 grid(D_INNER / 64, T_TOTAL / 64);
        dt_gemm<<<grid, 256, 0, stream>>>(dbc, W_dt, b_dt, dtbuf);
    }
    // 6. chunked selective scan (h-in-registers)
    {
        dim3 gridA(NC, D_INNER / 256, BATCH);   // 64 x 8 x 2 = 1024 blocks
        scanA<<<gridA, 256, 0, stream>>>(dbc, dtbuf, xc, A_log, hbuf, sdt);
        scanB<<<(BATCH * D_STATE * D_INNER) / 256, 256, 0, stream>>>(A_log, sdt, hbuf);
        scanC<<<gridA, 256, 0, stream>>>(dbc, dtbuf, xc, xz,
                                         A_log, D_skip, hbuf, ybf);
    }
    // cast W_out (reuse wbf region)
    cast_bf16_kernel<<<2048, 256, 0, stream>>>(W_out, wbf);

    // 7. out = y @ W_out^T (bf16 MFMA): M=2048, N=1024, K=2048
    {
        dim3 grid(1024 / 128, 2048 / 128);
        gemm_bf16_bt<<<grid, 256, 0, stream>>>(ybf, D_INNER, wbf, D_INNER,
                                               out, D_MODEL, D_INNER);
    }
}

// Round 12
// 269.637 us; speedup vs baseline: 7.4766x; 1.0790x over previous
//
#include <hip/hip_runtime.h>
#include <hip/hip_bf16.h>
#include <math.h>

// Problem constants
#define D_MODEL 1024
#define D_STATE 16
#define D_INNER 2048
#define DT_RANK 64
#define BATCH 2
#define SEQ_LEN 1024
#define T_TOTAL (BATCH * SEQ_LEN)   // 2048 rows

// Scan chunking: h[16] per thread, one thread per (b, chunk, d)
#define NC 64
#define CL 16

// W_x GEMM split-K
#define KS 16
#define KC 128
#define KT 64

typedef unsigned short u16;
typedef __bf16 bf16x8 __attribute__((ext_vector_type(8)));
typedef float f32x4 __attribute__((ext_vector_type(4)));

__device__ __forceinline__ u16 f2bf(float f) {
    unsigned u = __builtin_bit_cast(unsigned, f);
    u += 0x7FFFu + ((u >> 16) & 1u);   // RNE
    return (u16)(u >> 16);
}

#define GLOAD_LDS16(g, l) \
    __builtin_amdgcn_global_load_lds((const __attribute__((address_space(1))) void*)(g), \
                                     (__attribute__((address_space(3))) void*)(l), 16, 0, 0)

// ---------------------------------------------------------------------------
// fp32 -> bf16 cast covering two arrays in one launch.
// ---------------------------------------------------------------------------
__global__ __launch_bounds__(256) void cast2_bf16_kernel(
    const float* __restrict__ in0, u16* __restrict__ out0, int nb0,
    const float* __restrict__ in1, u16* __restrict__ out1)
{
    const float* in; u16* out; int i;
    if (blockIdx.x < nb0) { in = in0; out = out0; i = blockIdx.x * 256 + threadIdx.x; }
    else { in = in1; out = out1; i = (blockIdx.x - nb0) * 256 + threadIdx.x; }
    float4 v = ((const float4*)in)[i];
    unsigned lo = (unsigned)f2bf(v.x) | ((unsigned)f2bf(v.y) << 16);
    unsigned hi = (unsigned)f2bf(v.z) | ((unsigned)f2bf(v.w) << 16);
    ((uint2*)out)[i] = make_uint2(lo, hi);
}

__global__ __launch_bounds__(256) void cast_bf16_kernel(
    const float* __restrict__ in, u16* __restrict__ out)
{
    int i = blockIdx.x * 256 + threadIdx.x;
    float4 v = ((const float4*)in)[i];
    unsigned lo = (unsigned)f2bf(v.x) | ((unsigned)f2bf(v.y) << 16);
    unsigned hi = (unsigned)f2bf(v.z) | ((unsigned)f2bf(v.w) << 16);
    ((uint2*)out)[i] = make_uint2(lo, hi);
}

// ---------------------------------------------------------------------------
// bf16 MFMA GEMM, 8 waves (512 thr), 128x128 tile, BK=32.
// Wave grid 2x4; wave tile 64x32 (af[4] x bf[2], 8 MFMA/k-step).
// Optional K-split via gridDim.z: kbase = z*kchunk, C += z*csize.
// ---------------------------------------------------------------------------
__global__ __launch_bounds__(512) void gemm_bf16_8w(
    const u16* __restrict__ A, int lda,
    const u16* __restrict__ Bw, int ldb,
    float* __restrict__ C, int ldc, int kchunk, size_t csize)
{
    __shared__ u16 As[128][32];
    __shared__ u16 Bs[128][32];

    const int tid  = threadIdx.x;
    const int lane = tid & 63;
    const int wave = tid >> 6;          // 0..7
    const int wr   = wave >> 2;         // 0..1  (64-row half)
    const int wc   = wave & 3;          // 0..3  (32-col quarter)
    const int row0 = blockIdx.y * 128;
    const int col0 = blockIdx.x * 128;
    const int kbase = blockIdx.z * kchunk;

    C += (size_t)blockIdx.z * csize;

    // staging: 1 x 16B per thread per operand; 512 threads cover 128x32 u16
    const int srow = tid >> 2;          // 0..127
    const int scol = (tid & 3) * 8;

    const u16* ag = A  + (size_t)(row0 + srow) * lda + scol;
    const u16* bg = Bw + (size_t)(col0 + srow) * ldb + scol;
    u16* asl = &As[0][0] + wave * 512;  // wave w -> rows 16w..16w+15
    u16* bsl = &Bs[0][0] + wave * 512;

    f32x4 acc[4][2];
#pragma unroll
    for (int m = 0; m < 4; ++m)
#pragma unroll
        for (int n = 0; n < 2; ++n)
            acc[m][n] = (f32x4){0.f, 0.f, 0.f, 0.f};

    const int fr = lane & 15;
    const int kh = (lane >> 4) * 8;

    for (int k0 = kbase; k0 < kbase + kchunk; k0 += 32) {
        GLOAD_LDS16(ag + k0, asl);
        GLOAD_LDS16(bg + k0, bsl);
        __syncthreads();

        bf16x8 af[4], bf[2];
#pragma unroll
        for (int m = 0; m < 4; ++m)
            af[m] = *(const bf16x8*)&As[wr * 64 + m * 16 + fr][kh];
#pragma unroll
        for (int n = 0; n < 2; ++n)
            bf[n] = *(const bf16x8*)&Bs[wc * 32 + n * 16 + fr][kh];
#pragma unroll
        for (int m = 0; m < 4; ++m)
#pragma unroll
            for (int n = 0; n < 2; ++n)
                acc[m][n] = __builtin_amdgcn_mfma_f32_16x16x32_bf16(
                    af[m], bf[n], acc[m][n], 0, 0, 0);
        __syncthreads();
    }

    const int crow = (lane >> 4) * 4;
#pragma unroll
    for (int m = 0; m < 4; ++m) {
        const int gr = row0 + wr * 64 + m * 16 + crow;
#pragma unroll
        for (int n = 0; n < 2; ++n) {
            const int gc = col0 + wc * 32 + n * 16 + fr;
#pragma unroll
            for (int r = 0; r < 4; ++r)
                C[(size_t)(gr + r) * ldc + gc] = acc[m][n][r];
        }
    }
}

// out = p0 + p1, float4 per thread
__global__ __launch_bounds__(256) void reduce2_kernel(
    const float* __restrict__ part, float* __restrict__ out, size_t n4)
{
    size_t i = (size_t)blockIdx.x * 256 + threadIdx.x;
    float4 a = ((const float4*)part)[i];
    float4 b = ((const float4*)part)[i + n4];
    ((float4*)out)[i] = make_float4(a.x + b.x, a.y + b.y, a.z + b.z, a.w + b.w);
}

// ---------------------------------------------------------------------------
// Split-K fp32 GEMM for dbc = xc @ W_x^T (M=2048, N=96, K=2048).
// ---------------------------------------------------------------------------
__global__ __launch_bounds__(256) void wx_partial(
    const float* __restrict__ A,
    const float* __restrict__ Bw,
    float* __restrict__ part)
{
    __shared__ float As[32][68];
    __shared__ float Bs[KT][98];

    const int tid = threadIdx.x;
    const int ks  = blockIdx.x;
    const int m0  = blockIdx.y * 32;
    const int k0  = ks * KC;

    const int tx = tid & 15;
    const int ty = tid >> 4;

    float acc[2][6] = {};

    for (int kk = 0; kk < KC; kk += KT) {
#pragma unroll
        for (int i = 0; i < 2; ++i) {
            int slot = tid + i * 256;
            int m  = slot >> 4;
            int kq = slot & 15;
            float4 v = *(const float4*)&A[(size_t)(m0 + m) * D_INNER + k0 + kk + kq * 4];
            *(float4*)&As[m][kq * 4] = v;
        }
#pragma unroll
        for (int i = 0; i < 6; ++i) {
            int slot = tid + i * 256;
            int n  = slot >> 4;
            int kq = slot & 15;
            float4 v = *(const float4*)&Bw[(size_t)n * D_INNER + k0 + kk + kq * 4];
            Bs[kq * 4 + 0][n] = v.x;
            Bs[kq * 4 + 1][n] = v.y;
            Bs[kq * 4 + 2][n] = v.z;
            Bs[kq * 4 + 3][n] = v.w;
        }
        __syncthreads();

#pragma unroll 8
        for (int k = 0; k < KT; ++k) {
            float a0 = As[ty * 2 + 0][k];
            float a1 = As[ty * 2 + 1][k];
            float2 b0 = *(const float2*)&Bs[k][tx * 6 + 0];
            float2 b1 = *(const float2*)&Bs[k][tx * 6 + 2];
            float2 b2 = *(const float2*)&Bs[k][tx * 6 + 4];
            float bv[6] = {b0.x, b0.y, b1.x, b1.y, b2.x, b2.y};
#pragma unroll
            for (int j = 0; j < 6; ++j) {
                acc[0][j] += a0 * bv[j];
                acc[1][j] += a1 * bv[j];
            }
        }
        __syncthreads();
    }

#pragma unroll
    for (int i = 0; i < 2; ++i) {
        size_t base = ((size_t)ks * T_TOTAL + (m0 + ty * 2 + i)) * 96 + tx * 6;
#pragma unroll
        for (int j = 0; j < 6; ++j)
            part[base + j] = acc[i][j];
    }
}

__global__ __launch_bounds__(256) void wx_reduce(
    const float* __restrict__ part, float* __restrict__ dbc)
{
    int i = blockIdx.x * 256 + threadIdx.x;
    float s = 0.f;
#pragma unroll
    for (int ks = 0; ks < KS; ++ks)
        s += part[(size_t)ks * T_TOTAL * 96 + i];
    dbc[i] = s;
}

// ---------------------------------------------------------------------------
// dt GEMM + fused bias+softplus.
// ---------------------------------------------------------------------------
__global__ __launch_bounds__(256) void dt_gemm(
    const float* __restrict__ A,
    const float* __restrict__ Bw,
    const float* __restrict__ bdt,
    float* __restrict__ dtb)
{
    __shared__ float As[16][65];
    __shared__ float Bs[16][65];

    const int tid = threadIdx.x;
    const int row0 = blockIdx.y * 64;
    const int col0 = blockIdx.x * 64;
    const int ty = tid >> 4;
    const int tx = tid & 15;

    float acc[4][4] = {};

    for (int k0 = 0; k0 < DT_RANK; k0 += 16) {
#pragma unroll
        for (int i = 0; i < 4; ++i) {
            int idx = tid + i * 256;
            int m = idx >> 4;
            int k = idx & 15;
            As[k][m] = A[(size_t)(row0 + m) * 96 + (k0 + k)];
        }
#pragma unroll
        for (int i = 0; i < 4; ++i) {
            int idx = tid + i * 256;
            int n = idx >> 4;
            int k = idx & 15;
            Bs[k][n] = Bw[(size_t)(col0 + n) * DT_RANK + (k0 + k)];
        }
        __syncthreads();

#pragma unroll
        for (int k = 0; k < 16; ++k) {
            float a[4], b[4];
#pragma unroll
            for (int i = 0; i < 4; ++i) a[i] = As[k][ty * 4 + i];
#pragma unroll
            for (int j = 0; j < 4; ++j) b[j] = Bs[k][tx * 4 + j];
#pragma unroll
            for (int i = 0; i < 4; ++i)
#pragma unroll
                for (int j = 0; j < 4; ++j)
                    acc[i][j] += a[i] * b[j];
        }
        __syncthreads();
    }

#pragma unroll
    for (int i = 0; i < 4; ++i) {
        int gm = row0 + ty * 4 + i;
#pragma unroll
        for (int j = 0; j < 4; ++j) {
            int gn = col0 + tx * 4 + j;
            float xv = acc[i][j] + bdt[gn];
            float sp = (xv > 20.f) ? xv : log1pf(__expf(xv));
            dtb[(size_t)gm * D_INNER + gn] = sp;
        }
    }
}

// ---------------------------------------------------------------------------
// Causal depthwise conv (K=4) + bias + SiLU.
// ---------------------------------------------------------------------------
__global__ __launch_bounds__(256) void conv_silu_kernel(
    const float* __restrict__ xz,
    const float* __restrict__ cw,
    const float* __restrict__ cb,
    float* __restrict__ xc)
{
    int idx = blockIdx.x * 256 + threadIdx.x;
    int d = idx & (D_INNER - 1);
    int t = (idx >> 11) & (SEQ_LEN - 1);
    int b = idx >> 21;

    const float* base = xz + ((size_t)b * SEQ_LEN + t) * (2 * D_INNER) + d;
    float w0 = cw[d * 4 + 0], w1 = cw[d * 4 + 1], w2 = cw[d * 4 + 2], w3 = cw[d * 4 + 3];
    float acc = cb[d];
    if (t >= 3) acc += w0 * base[-3 * (2 * D_INNER)];
    if (t >= 2) acc += w1 * base[-2 * (2 * D_INNER)];
    if (t >= 1) acc += w2 * base[-1 * (2 * D_INNER)];
    acc += w3 * base[0];
    float s = acc / (1.f + __expf(-acc));
    xc[idx] = s;
}

// ---------------------------------------------------------------------------
// Chunked selective scan, h[16]-in-registers (R10-validated).
// ---------------------------------------------------------------------------
__global__ __launch_bounds__(256) void scanA(
    const float* __restrict__ dbc,
    const float* __restrict__ dtv,
    const float* __restrict__ xc,
    const float* __restrict__ A_log,
    float* __restrict__ hbuf,
    float* __restrict__ sdt)
{
    __shared__ float sB[CL][16];

    const int tid = threadIdx.x;
    const int c = blockIdx.x;
    const int b = blockIdx.z;
    const int d = blockIdx.y * 256 + tid;
    const int t0 = c * CL;

    {
        int t = tid >> 4, e = tid & 15;
        sB[t][e] = dbc[(size_t)(b * SEQ_LEN + t0 + t) * 96 + DT_RANK + e];
    }

    float A[16];
#pragma unroll
    for (int i = 0; i < 4; ++i) {
        float4 v = *(const float4*)&A_log[d * 16 + i * 4];
        A[i * 4 + 0] = -__expf(v.x);
        A[i * 4 + 1] = -__expf(v.y);
        A[i * 4 + 2] = -__expf(v.z);
        A[i * 4 + 3] = -__expf(v.w);
    }
    __syncthreads();

    float h[16];
#pragma unroll
    for (int n = 0; n < 16; ++n) h[n] = 0.f;
    float sum = 0.f;

#pragma unroll 4
    for (int t = 0; t < CL; ++t) {
        size_t row = (size_t)(b * SEQ_LEN + t0 + t);
        float dtval = dtv[row * D_INNER + d];
        float xv    = xc [row * D_INNER + d];
        float w = xv * dtval;
        sum += dtval;
#pragma unroll
        for (int n = 0; n < 16; ++n) {
            float a = __expf(dtval * A[n]);
            h[n] = a * h[n] + w * sB[t][n];
        }
    }

    size_t o = (size_t)(b * NC + c) * 16 * D_INNER + d;
#pragma unroll
    for (int n = 0; n < 16; ++n)
        hbuf[o + (size_t)n * D_INNER] = h[n];
    sdt[(size_t)(b * NC + c) * D_INNER + d] = sum;
}

__global__ __launch_bounds__(256) void scanB(
    const float* __restrict__ A_log,
    const float* __restrict__ sdt,
    float* __restrict__ hbuf)
{
    int idx = blockIdx.x * 256 + threadIdx.x;
    int b  = idx >> 15;
    int nd = idx & 32767;
    int n  = nd >> 11;
    int d  = nd & (D_INNER - 1);

    const float A = -__expf(A_log[d * 16 + n]);
    float h = 0.f;
#pragma unroll 8
    for (int c = 0; c < NC; ++c) {
        size_t o = ((size_t)(b * NC + c) * 16 + n) * D_INNER + d;
        float tmp = hbuf[o];
        float P = __expf(A * sdt[(size_t)(b * NC + c) * D_INNER + d]);
        hbuf[o] = h;
        h = P * h + tmp;
    }
}

__global__ __launch_bounds__(256) void scanC(
    const float* __restrict__ dbc,
    const float* __restrict__ dtv,
    const float* __restrict__ xc,
    const float* __restrict__ xz,
    const float* __restrict__ A_log,
    const float* __restrict__ D_skip,
    const float* __restrict__ hbuf,
    u16* __restrict__ y)
{
    __shared__ float sB[CL][16];
    __shared__ float sC[CL][16];

    const int tid = threadIdx.x;
    const int c = blockIdx.x;
    const int b = blockIdx.z;
    const int d = blockIdx.y * 256 + tid;
    const int t0 = c * CL;

    {
        int t = tid >> 4, e = tid & 15;
        size_t row = (size_t)(b * SEQ_LEN + t0 + t);
        sB[t][e] = dbc[row * 96 + DT_RANK + e];
        sC[t][e] = dbc[row * 96 + DT_RANK + D_STATE + e];
    }

    float A[16];
#pragma unroll
    for (int i = 0; i < 4; ++i) {
        float4 v = *(const float4*)&A_log[d * 16 + i * 4];
        A[i * 4 + 0] = -__expf(v.x);
        A[i * 4 + 1] = -__expf(v.y);
        A[i * 4 + 2] = -__expf(v.z);
        A[i * 4 + 3] = -__expf(v.w);
    }
    const float Dv = D_skip[d];

    float h[16];
    size_t ho = (size_t)(b * NC + c) * 16 * D_INNER + d;
#pragma unroll
    for (int n = 0; n < 16; ++n)
        h[n] = hbuf[ho + (size_t)n * D_INNER];
    __syncthreads();

#pragma unroll 4
    for (int t = 0; t < CL; ++t) {
        size_t row = (size_t)(b * SEQ_LEN + t0 + t);
        float dtval = dtv[row * D_INNER + d];
        float xv    = xc [row * D_INNER + d];
        float zv    = xz [row * (2 * D_INNER) + D_INNER + d];
        float w = xv * dtval;
        float yv = 0.f;
#pragma unroll
        for (int n = 0; n < 16; ++n) {
            float a = __expf(dtval * A[n]);
            h[n] = a * h[n] + w * sB[t][n];
            yv += sC[t][n] * h[n];
        }
        float sig = 1.f / (1.f + __expf(-zv));
        y[row * D_INNER + d] = f2bf((yv + xv * Dv) * (zv * sig));
    }
}

// ---------------------------------------------------------------------------
// Launch
// ---------------------------------------------------------------------------
extern "C" void kernel_launch(void* const* d_in, const int* in_sizes, int n_in,
                              void* d_out, int out_size, void* d_ws, size_t ws_size,
                              hipStream_t stream)
{
    const float* x      = (const float*)d_in[0];
    const float* W_in   = (const float*)d_in[1];
    const float* conv_w = (const float*)d_in[2];
    const float* conv_b = (const float*)d_in[3];
    const float* W_x    = (const float*)d_in[4];
    const float* W_dt   = (const float*)d_in[5];
    const float* b_dt   = (const float*)d_in[6];
    const float* A_log  = (const float*)d_in[7];
    const float* D_skip = (const float*)d_in[8];
    const float* W_out  = (const float*)d_in[9];
    float* out = (float*)d_out;

    float* ws = (float*)d_ws;
    float* xz    = ws;                                  // 8,388,608 f
    float* xc    = xz + (size_t)8388608;                // 4,194,304 f
    float* dbc   = xc + (size_t)4194304;                //   196,608 f
    float* dtbuf = dbc + (size_t)196608;                // 4,194,304 f
    float* hbuf  = dtbuf + (size_t)4194304;             // 4,194,304 f
    float* sdt   = hbuf + (size_t)4194304;              //   262,144 f
    u16* ybf = (u16*)(sdt + (size_t)262144);            // 4,194,304 u16
    u16* xbf = ybf + (size_t)4194304;                   // 2,097,152 u16
    u16* wbf = xbf + (size_t)2097152;                   // 4,194,304 u16
    // wx split-K partials alias dtbuf (consumed before dt_gemm writes dtbuf).
    float* part = dtbuf;
    // GEMM7 split-K partials alias hbuf (scan complete by then); 2*2M floats.
    float* part7 = hbuf;

    // casts for GEMM1 (one launch: x 2M elems -> 2048 blocks, W_in 4M -> 4096)
    cast2_bf16_kernel<<<6144, 256, 0, stream>>>(x, xbf, 2048, W_in, wbf);

    // 1. xz = x @ W_in^T (bf16 MFMA, 8-wave): M=2048, N=4096, K=1024
    {
        dim3 grid(4096 / 128, 2048 / 128, 1);   // 512 blocks
        gemm_bf16_8w<<<grid, 512, 0, stream>>>(xbf, D_MODEL, wbf, D_MODEL,
                                               xz, 2 * D_INNER, D_MODEL, 0);
    }
    // 2. conv + silu
    conv_silu_kernel<<<(T_TOTAL * D_INNER) / 256, 256, 0, stream>>>(xz, conv_w, conv_b, xc);

    // 3. dbc = xc @ W_x^T : split-K fp32
    {
        dim3 grid(KS, T_TOTAL / 32);
        wx_partial<<<grid, 256, 0, stream>>>(xc, W_x, part);
        wx_reduce<<<(T_TOTAL * 96) / 256, 256, 0, stream>>>(part, dbc);
    }
    // 4+5. dt = softplus(dbc[:, :64] @ W_dt^T + b_dt)  (fused)
    {
        dim3 grid(D_INNER / 64, T_TOTAL / 64);
        dt_gemm<<<grid, 256, 0, stream>>>(dbc, W_dt, b_dt, dtbuf);
    }
    // 6. chunked selective scan (h-in-registers)
    {
        dim3 gridA(NC, D_INNER / 256, BATCH);
        scanA<<<gridA, 256, 0, stream>>>(dbc, dtbuf, xc, A_log, hbuf, sdt);
        scanB<<<(BATCH * D_STATE * D_INNER) / 256, 256, 0, stream>>>(A_log, sdt, hbuf);
        scanC<<<gridA, 256, 0, stream>>>(dbc, dtbuf, xc, xz,
                                         A_log, D_skip, hbuf, ybf);
    }
    // cast W_out (into wbf; W_in copy no longer needed)
    cast_bf16_kernel<<<2048, 256, 0, stream>>>(W_out, wbf);

    // 7. out = y @ W_out^T (bf16 MFMA, 8-wave, split-K=2): M=2048, N=1024, K=2048
    {
        dim3 grid(1024 / 128, 2048 / 128, 2);   // 256 blocks
        gemm_bf16_8w<<<grid, 512, 0, stream>>>(ybf, D_INNER, wbf, D_INNER,
                                               part7, D_MODEL, 1024,
                                               (size_t)T_TOTAL * D_MODEL);
        reduce2_kernel<<<(T_TOTAL * D_MODEL / 4) / 256, 256, 0, stream>>>(
            part7, out, (size_t)T_TOTAL * D_MODEL / 4);
    }
}